// Round 1
// baseline (11191.964 us; speedup 1.0000x reference)
//
#include <hip/hip_runtime.h>

#define BN_EPS 1e-5f

// ---------------------------------------------------------------------------
// Edge aggregation: agg[dst[e]] += x[src[e]]  (segment_sum)
// One thread per edge; float4 gathers from x; per-float atomicAdd into agg.
// ---------------------------------------------------------------------------
template<int F>
__global__ void edge_agg(const int* __restrict__ src, const int* __restrict__ dst,
                         const float* __restrict__ x, float* __restrict__ agg, int E) {
    int e = blockIdx.x * blockDim.x + threadIdx.x;
    if (e >= E) return;
    int s = src[e];
    int d = dst[e];
    const float4* xs = (const float4*)(x + (size_t)s * F);
    float* ad = agg + (size_t)d * F;
#pragma unroll
    for (int q = 0; q < F / 4; q++) {
        float4 v = xs[q];
        atomicAdd(ad + q * 4 + 0, v.x);
        atomicAdd(ad + q * 4 + 1, v.y);
        atomicAdd(ad + q * 4 + 2, v.z);
        atomicAdd(ad + q * 4 + 3, v.w);
    }
}

// ---------------------------------------------------------------------------
// Node MLP: z = mlp2(act(mlp1((1+eps)*x + agg))) + residual(x)
// Also accumulates per-channel sum / sumsq for BN into stats[0:16]/stats[16:32]
// via wave-shuffle reduction + global atomics.
// FIN in {8,16}; output width fixed at 16. LEAKY selects LeakyReLU(0.01) vs ReLU.
// ---------------------------------------------------------------------------
template<int FIN, bool LEAKY>
__global__ void node_mlp(const float* __restrict__ x, const float* __restrict__ agg,
                         const float* __restrict__ epsp,
                         const float* __restrict__ w1, const float* __restrict__ b1,
                         const float* __restrict__ w2, const float* __restrict__ b2,
                         const float* __restrict__ rw, const float* __restrict__ rb,
                         float* __restrict__ z, float* __restrict__ stats, int n) {
    __shared__ float sw1[FIN * 16], sw2[16 * 16], srw[FIN * 16];
    __shared__ float sb1[16], sb2[16], srb[16];
    int t = threadIdx.x;
    for (int i = t; i < FIN * 16; i += blockDim.x) { sw1[i] = w1[i]; srw[i] = rw[i]; }
    for (int i = t; i < 16 * 16; i += blockDim.x) sw2[i] = w2[i];
    if (t < 16) { sb1[t] = b1[t]; sb2[t] = b2[t]; srb[t] = rb[t]; }
    __syncthreads();

    float epsf = 1.0f + epsp[0];
    int i = blockIdx.x * blockDim.x + t;

    float zv[16];
    if (i < n) {
        float xin[FIN], hin[FIN];
        const float4* xr = (const float4*)(x + (size_t)i * FIN);
        const float4* ar = (const float4*)(agg + (size_t)i * FIN);
#pragma unroll
        for (int q = 0; q < FIN / 4; q++) {
            float4 xv = xr[q];
            float4 av = ar[q];
            xin[q * 4 + 0] = xv.x; xin[q * 4 + 1] = xv.y;
            xin[q * 4 + 2] = xv.z; xin[q * 4 + 3] = xv.w;
            hin[q * 4 + 0] = epsf * xv.x + av.x;
            hin[q * 4 + 1] = epsf * xv.y + av.y;
            hin[q * 4 + 2] = epsf * xv.z + av.z;
            hin[q * 4 + 3] = epsf * xv.w + av.w;
        }
        float mid[16];
#pragma unroll
        for (int j = 0; j < 16; j++) {
            float acc = sb1[j];
#pragma unroll
            for (int k = 0; k < FIN; k++) acc += hin[k] * sw1[k * 16 + j];
            mid[j] = LEAKY ? (acc > 0.0f ? acc : 0.01f * acc) : fmaxf(acc, 0.0f);
        }
#pragma unroll
        for (int j = 0; j < 16; j++) {
            float acc = sb2[j] + srb[j];
#pragma unroll
            for (int k = 0; k < 16; k++) acc += mid[k] * sw2[k * 16 + j];
#pragma unroll
            for (int k = 0; k < FIN; k++) acc += xin[k] * srw[k * 16 + j];
            zv[j] = acc;
        }
        float4* zr = (float4*)(z + (size_t)i * 16);
#pragma unroll
        for (int q = 0; q < 4; q++)
            zr[q] = make_float4(zv[q * 4 + 0], zv[q * 4 + 1], zv[q * 4 + 2], zv[q * 4 + 3]);
    } else {
#pragma unroll
        for (int j = 0; j < 16; j++) zv[j] = 0.0f;
    }

    // per-wave reduction of sum and sumsq for each of 16 channels, then atomic
#pragma unroll
    for (int c = 0; c < 16; c++) {
        float s = zv[c];
        float q = zv[c] * zv[c];
        for (int off = 32; off > 0; off >>= 1) {
            s += __shfl_down(s, off);
            q += __shfl_down(q, off);
        }
        if ((t & 63) == 0) {
            atomicAdd(&stats[c], s);
            atomicAdd(&stats[16 + c], q);
        }
    }
}

// ---------------------------------------------------------------------------
// BN apply: out = (z - mean) * rsqrt(var + eps) * gamma + beta
// mean/var derived from stats (sum, sumsq).
// ---------------------------------------------------------------------------
__global__ void bn_apply(const float* __restrict__ z, const float* __restrict__ stats,
                         const float* __restrict__ g, const float* __restrict__ be,
                         float* __restrict__ out, int n, float inv_n) {
    __shared__ float sc[16], sh[16];
    int t = threadIdx.x;
    if (t < 16) {
        float mean = stats[t] * inv_n;
        float var = stats[16 + t] * inv_n - mean * mean;
        float s = rsqrtf(var + BN_EPS) * g[t];
        sc[t] = s;
        sh[t] = be[t] - mean * s;
    }
    __syncthreads();
    int i = blockIdx.x * blockDim.x + t;
    if (i >= n) return;
    const float4* zr = (const float4*)(z + (size_t)i * 16);
    float4* orow = (float4*)(out + (size_t)i * 16);
#pragma unroll
    for (int q = 0; q < 4; q++) {
        float4 v = zr[q];
        v.x = v.x * sc[q * 4 + 0] + sh[q * 4 + 0];
        v.y = v.y * sc[q * 4 + 1] + sh[q * 4 + 1];
        v.z = v.z * sc[q * 4 + 2] + sh[q * 4 + 2];
        v.w = v.w * sc[q * 4 + 3] + sh[q * 4 + 3];
        orow[q] = v;
    }
}

extern "C" void kernel_launch(void* const* d_in, const int* in_sizes, int n_in,
                              void* d_out, int out_size, void* d_ws, size_t ws_size,
                              hipStream_t stream) {
    const float* x = (const float*)d_in[0];
    const int* ei = (const int*)d_in[1];
    const int E = in_sizes[1] / 2;
    const int n = in_sizes[0] / 8;
    const int* src = ei;
    const int* dst = ei + E;

    // layer params
    const float* eps1 = (const float*)d_in[2];
    const float* w11 = (const float*)d_in[3];  const float* b11 = (const float*)d_in[4];
    const float* w12 = (const float*)d_in[5];  const float* b12 = (const float*)d_in[6];
    const float* rw1 = (const float*)d_in[7];  const float* rb1 = (const float*)d_in[8];
    const float* g1  = (const float*)d_in[9];  const float* be1 = (const float*)d_in[10];

    const float* eps2 = (const float*)d_in[11];
    const float* w21 = (const float*)d_in[12]; const float* b21 = (const float*)d_in[13];
    const float* w22 = (const float*)d_in[14]; const float* b22 = (const float*)d_in[15];
    const float* rw2 = (const float*)d_in[16]; const float* rb2 = (const float*)d_in[17];
    const float* g2  = (const float*)d_in[18]; const float* be2 = (const float*)d_in[19];

    const float* eps3 = (const float*)d_in[20];
    const float* w31 = (const float*)d_in[21]; const float* b31 = (const float*)d_in[22];
    const float* w32 = (const float*)d_in[23]; const float* b32 = (const float*)d_in[24];
    const float* rw3 = (const float*)d_in[25]; const float* rb3 = (const float*)d_in[26];
    const float* g3  = (const float*)d_in[27]; const float* be3 = (const float*)d_in[28];

    float* out = (float*)d_out;
    float* ws = (float*)d_ws;

    // workspace layout (floats): agg[n*16] | stats[32] | z[n*16] | hA[n*16] | hB[n*16]
    float* agg = ws;
    float* stats = ws + (size_t)n * 16;
    float* z = stats + 32;
    float* hA = z + (size_t)n * 16;
    float* hB = hA + (size_t)n * 16;

    const float inv_n = 1.0f / (float)n;
    const int eb = 256, egrid = (E + eb - 1) / eb;
    const int nb = 256, ngrid = (n + nb - 1) / nb;
    const size_t zero_bytes = ((size_t)n * 16 + 32) * sizeof(float);

    // ---- layer 1 (FIN=8, LeakyReLU) ----
    hipMemsetAsync(ws, 0, zero_bytes, stream);
    edge_agg<8><<<egrid, eb, 0, stream>>>(src, dst, x, agg, E);
    node_mlp<8, true><<<ngrid, nb, 0, stream>>>(x, agg, eps1, w11, b11, w12, b12,
                                                rw1, rb1, z, stats, n);
    bn_apply<<<ngrid, nb, 0, stream>>>(z, stats, g1, be1, hA, n, inv_n);

    // ---- layer 2 (FIN=16, ReLU) ----
    hipMemsetAsync(ws, 0, zero_bytes, stream);
    edge_agg<16><<<egrid, eb, 0, stream>>>(src, dst, hA, agg, E);
    node_mlp<16, false><<<ngrid, nb, 0, stream>>>(hA, agg, eps2, w21, b21, w22, b22,
                                                  rw2, rb2, z, stats, n);
    bn_apply<<<ngrid, nb, 0, stream>>>(z, stats, g2, be2, hB, n, inv_n);

    // ---- layer 3 (FIN=16, ReLU) ----
    hipMemsetAsync(ws, 0, zero_bytes, stream);
    edge_agg<16><<<egrid, eb, 0, stream>>>(src, dst, hB, agg, E);
    node_mlp<16, false><<<ngrid, nb, 0, stream>>>(hB, agg, eps3, w31, b31, w32, b32,
                                                  rw3, rb3, z, stats, n);
    bn_apply<<<ngrid, nb, 0, stream>>>(z, stats, g3, be3, out, n, inv_n);
}

// Round 2
// 1937.561 us; speedup vs baseline: 5.7763x; 5.7763x over previous
//
#include <hip/hip_runtime.h>

#define BN_EPS 1e-5f
#define SCAN_B 256

// ---------------------------------------------------------------------------
// CSR build: degree histogram -> exclusive scan -> slot fill
// ---------------------------------------------------------------------------
__global__ void hist_deg(const int* __restrict__ dst, int* __restrict__ deg, int E) {
    int e = blockIdx.x * blockDim.x + threadIdx.x;
    if (e >= E) return;
    atomicAdd(&deg[dst[e]], 1);
}

// per-block exclusive scan of deg -> part; block totals -> bsum
__global__ void scan_block(const int* __restrict__ deg, int* __restrict__ part,
                           int* __restrict__ bsum, int n) {
    __shared__ int s[SCAN_B];
    int t = threadIdx.x;
    int i = blockIdx.x * SCAN_B + t;
    int v = (i < n) ? deg[i] : 0;
    s[t] = v;
    __syncthreads();
    for (int off = 1; off < SCAN_B; off <<= 1) {
        int a = (t >= off) ? s[t - off] : 0;
        __syncthreads();
        s[t] += a;
        __syncthreads();
    }
    if (i < n) part[i] = s[t] - v;  // exclusive within block
    if (t == SCAN_B - 1) bsum[blockIdx.x] = s[t];
}

// single-block exclusive scan of block sums (nb <= 512)
__global__ void scan_bsum(int* __restrict__ bsum, int nb) {
    __shared__ int s[512];
    int t = threadIdx.x;
    int v = (t < nb) ? bsum[t] : 0;
    s[t] = v;
    __syncthreads();
    for (int off = 1; off < 512; off <<= 1) {
        int a = (t >= off) ? s[t - off] : 0;
        __syncthreads();
        s[t] += a;
        __syncthreads();
    }
    if (t < nb) bsum[t] = s[t] - v;
}

// add block offsets: row_start[i] = part[i] + bsum[b]; cursor copy
__global__ void scan_add(int* __restrict__ part, const int* __restrict__ bsum,
                         int* __restrict__ cursor, int n) {
    int i = blockIdx.x * SCAN_B + threadIdx.x;
    if (i >= n) return;
    int v = part[i] + bsum[blockIdx.x];
    part[i] = v;
    cursor[i] = v;
}

__global__ void fill_csr(const int* __restrict__ src, const int* __restrict__ dst,
                         int* __restrict__ cursor, int* __restrict__ csr_src, int E) {
    int e = blockIdx.x * blockDim.x + threadIdx.x;
    if (e >= E) return;
    int d = dst[e];
    int pos = atomicAdd(&cursor[d], 1);
    csr_src[pos] = src[e];
}

// ---------------------------------------------------------------------------
// Gather aggregation: F lanes per node (one per channel); neighbor rows are
// read as coalesced F*4-byte lines; csr index loads broadcast across lanes.
// ---------------------------------------------------------------------------
template<int F>
__global__ void gather_agg(const int* __restrict__ row_start, const int* __restrict__ deg,
                           const int* __restrict__ csr_src, const float* __restrict__ x,
                           float* __restrict__ agg, int n) {
    int c = threadIdx.x % F;
    int node = blockIdx.x * (blockDim.x / F) + threadIdx.x / F;
    if (node >= n) return;
    int base = row_start[node];
    int d = deg[node];
    float acc = 0.0f;
    int k = 0;
    for (; k + 3 < d; k += 4) {
        int s0 = csr_src[base + k + 0];
        int s1 = csr_src[base + k + 1];
        int s2 = csr_src[base + k + 2];
        int s3 = csr_src[base + k + 3];
        acc += x[(size_t)s0 * F + c];
        acc += x[(size_t)s1 * F + c];
        acc += x[(size_t)s2 * F + c];
        acc += x[(size_t)s3 * F + c];
    }
    for (; k < d; k++) {
        int s = csr_src[base + k];
        acc += x[(size_t)s * F + c];
    }
    agg[(size_t)node * F + c] = acc;
}

// ---------------------------------------------------------------------------
// Node MLP: z = mlp2(act(mlp1((1+eps)*x + agg))) + residual(x)
// Accumulates per-channel sum/sumsq for BN into stats via wave reduce+atomics.
// NOTE: z may alias agg only when FIN == 16 (per-row in-place).
// ---------------------------------------------------------------------------
template<int FIN, bool LEAKY>
__global__ void node_mlp(const float* __restrict__ x, const float* __restrict__ agg,
                         const float* __restrict__ epsp,
                         const float* __restrict__ w1, const float* __restrict__ b1,
                         const float* __restrict__ w2, const float* __restrict__ b2,
                         const float* __restrict__ rw, const float* __restrict__ rb,
                         float* __restrict__ z, float* __restrict__ stats, int n) {
    __shared__ float sw1[FIN * 16], sw2[16 * 16], srw[FIN * 16];
    __shared__ float sb1[16], sb2[16], srb[16];
    int t = threadIdx.x;
    for (int i = t; i < FIN * 16; i += blockDim.x) { sw1[i] = w1[i]; srw[i] = rw[i]; }
    for (int i = t; i < 16 * 16; i += blockDim.x) sw2[i] = w2[i];
    if (t < 16) { sb1[t] = b1[t]; sb2[t] = b2[t]; srb[t] = rb[t]; }
    __syncthreads();

    float epsf = 1.0f + epsp[0];
    int i = blockIdx.x * blockDim.x + t;

    float zv[16];
    if (i < n) {
        float xin[FIN], hin[FIN];
        const float4* xr = (const float4*)(x + (size_t)i * FIN);
        const float4* ar = (const float4*)(agg + (size_t)i * FIN);
#pragma unroll
        for (int q = 0; q < FIN / 4; q++) {
            float4 xv = xr[q];
            float4 av = ar[q];
            xin[q * 4 + 0] = xv.x; xin[q * 4 + 1] = xv.y;
            xin[q * 4 + 2] = xv.z; xin[q * 4 + 3] = xv.w;
            hin[q * 4 + 0] = epsf * xv.x + av.x;
            hin[q * 4 + 1] = epsf * xv.y + av.y;
            hin[q * 4 + 2] = epsf * xv.z + av.z;
            hin[q * 4 + 3] = epsf * xv.w + av.w;
        }
        float mid[16];
#pragma unroll
        for (int j = 0; j < 16; j++) {
            float acc = sb1[j];
#pragma unroll
            for (int k = 0; k < FIN; k++) acc += hin[k] * sw1[k * 16 + j];
            mid[j] = LEAKY ? (acc > 0.0f ? acc : 0.01f * acc) : fmaxf(acc, 0.0f);
        }
#pragma unroll
        for (int j = 0; j < 16; j++) {
            float acc = sb2[j] + srb[j];
#pragma unroll
            for (int k = 0; k < 16; k++) acc += mid[k] * sw2[k * 16 + j];
#pragma unroll
            for (int k = 0; k < FIN; k++) acc += xin[k] * srw[k * 16 + j];
            zv[j] = acc;
        }
        float4* zr = (float4*)(z + (size_t)i * 16);
#pragma unroll
        for (int q = 0; q < 4; q++)
            zr[q] = make_float4(zv[q * 4 + 0], zv[q * 4 + 1], zv[q * 4 + 2], zv[q * 4 + 3]);
    } else {
#pragma unroll
        for (int j = 0; j < 16; j++) zv[j] = 0.0f;
    }

#pragma unroll
    for (int c = 0; c < 16; c++) {
        float s = zv[c];
        float q = zv[c] * zv[c];
        for (int off = 32; off > 0; off >>= 1) {
            s += __shfl_down(s, off);
            q += __shfl_down(q, off);
        }
        if ((t & 63) == 0) {
            atomicAdd(&stats[c], s);
            atomicAdd(&stats[16 + c], q);
        }
    }
}

// ---------------------------------------------------------------------------
// BN apply
// ---------------------------------------------------------------------------
__global__ void bn_apply(const float* __restrict__ z, const float* __restrict__ stats,
                         const float* __restrict__ g, const float* __restrict__ be,
                         float* __restrict__ out, int n, float inv_n) {
    __shared__ float sc[16], sh[16];
    int t = threadIdx.x;
    if (t < 16) {
        float mean = stats[t] * inv_n;
        float var = stats[16 + t] * inv_n - mean * mean;
        float s = rsqrtf(var + BN_EPS) * g[t];
        sc[t] = s;
        sh[t] = be[t] - mean * s;
    }
    __syncthreads();
    int i = blockIdx.x * blockDim.x + t;
    if (i >= n) return;
    const float4* zr = (const float4*)(z + (size_t)i * 16);
    float4* orow = (float4*)(out + (size_t)i * 16);
#pragma unroll
    for (int q = 0; q < 4; q++) {
        float4 v = zr[q];
        v.x = v.x * sc[q * 4 + 0] + sh[q * 4 + 0];
        v.y = v.y * sc[q * 4 + 1] + sh[q * 4 + 1];
        v.z = v.z * sc[q * 4 + 2] + sh[q * 4 + 2];
        v.w = v.w * sc[q * 4 + 3] + sh[q * 4 + 3];
        orow[q] = v;
    }
}

extern "C" void kernel_launch(void* const* d_in, const int* in_sizes, int n_in,
                              void* d_out, int out_size, void* d_ws, size_t ws_size,
                              hipStream_t stream) {
    const float* x = (const float*)d_in[0];
    const int* ei = (const int*)d_in[1];
    const int E = in_sizes[1] / 2;
    const int n = in_sizes[0] / 8;
    const int* src = ei;
    const int* dst = ei + E;

    const float* eps1 = (const float*)d_in[2];
    const float* w11 = (const float*)d_in[3];  const float* b11 = (const float*)d_in[4];
    const float* w12 = (const float*)d_in[5];  const float* b12 = (const float*)d_in[6];
    const float* rw1 = (const float*)d_in[7];  const float* rb1 = (const float*)d_in[8];
    const float* g1  = (const float*)d_in[9];  const float* be1 = (const float*)d_in[10];

    const float* eps2 = (const float*)d_in[11];
    const float* w21 = (const float*)d_in[12]; const float* b21 = (const float*)d_in[13];
    const float* w22 = (const float*)d_in[14]; const float* b22 = (const float*)d_in[15];
    const float* rw2 = (const float*)d_in[16]; const float* rb2 = (const float*)d_in[17];
    const float* g2  = (const float*)d_in[18]; const float* be2 = (const float*)d_in[19];

    const float* eps3 = (const float*)d_in[20];
    const float* w31 = (const float*)d_in[21]; const float* b31 = (const float*)d_in[22];
    const float* w32 = (const float*)d_in[23]; const float* b32 = (const float*)d_in[24];
    const float* rw3 = (const float*)d_in[25]; const float* rb3 = (const float*)d_in[26];
    const float* g3  = (const float*)d_in[27]; const float* be3 = (const float*)d_in[28];

    float* out = (float*)d_out;
    float* ws = (float*)d_ws;

    // ws layout (floats then ints):
    // agg[n*16] | hA[n*16] | stats[32] || deg[n] | row_start[n] | cursor[n] | bsum[512] | csr[E]
    float* agg = ws;
    float* hA = agg + (size_t)n * 16;
    float* stats = hA + (size_t)n * 16;
    int* deg = (int*)(stats + 32);
    int* row_start = deg + n;
    int* cursor = row_start + n;
    int* bsum = cursor + n;
    int* csr = bsum + 512;

    const float inv_n = 1.0f / (float)n;
    const int eb = 256, egrid = (E + eb - 1) / eb;
    const int nb = 256, ngrid = (n + nb - 1) / nb;
    const int sgrid = (n + SCAN_B - 1) / SCAN_B;  // 391 for n=100000

    // ---- CSR build (once, reused by all 3 layers) ----
    hipMemsetAsync(deg, 0, (size_t)n * sizeof(int), stream);
    hist_deg<<<egrid, eb, 0, stream>>>(dst, deg, E);
    scan_block<<<sgrid, SCAN_B, 0, stream>>>(deg, row_start, bsum, n);
    scan_bsum<<<1, 512, 0, stream>>>(bsum, sgrid);
    scan_add<<<sgrid, SCAN_B, 0, stream>>>(row_start, bsum, cursor, n);
    fill_csr<<<egrid, eb, 0, stream>>>(src, dst, cursor, csr, E);

    // ---- layer 1 (FIN=8, LeakyReLU): agg8 lives in hA; z lives in agg ----
    hipMemsetAsync(stats, 0, 32 * sizeof(float), stream);
    gather_agg<8><<<(n * 8 + 255) / 256, 256, 0, stream>>>(row_start, deg, csr, x, hA, n);
    node_mlp<8, true><<<ngrid, nb, 0, stream>>>(x, hA, eps1, w11, b11, w12, b12,
                                                rw1, rb1, agg, stats, n);
    bn_apply<<<ngrid, nb, 0, stream>>>(agg, stats, g1, be1, hA, n, inv_n);

    // ---- layer 2 (FIN=16, ReLU): z aliases agg (per-row safe); hB = d_out ----
    hipMemsetAsync(stats, 0, 32 * sizeof(float), stream);
    gather_agg<16><<<(n * 16 + 255) / 256, 256, 0, stream>>>(row_start, deg, csr, hA, agg, n);
    node_mlp<16, false><<<ngrid, nb, 0, stream>>>(hA, agg, eps2, w21, b21, w22, b22,
                                                  rw2, rb2, agg, stats, n);
    bn_apply<<<ngrid, nb, 0, stream>>>(agg, stats, g2, be2, out, n, inv_n);

    // ---- layer 3 (FIN=16, ReLU): input = d_out, z aliases agg ----
    hipMemsetAsync(stats, 0, 32 * sizeof(float), stream);
    gather_agg<16><<<(n * 16 + 255) / 256, 256, 0, stream>>>(row_start, deg, csr, out, agg, n);
    node_mlp<16, false><<<ngrid, nb, 0, stream>>>(out, agg, eps3, w31, b31, w32, b32,
                                                  rw3, rb3, agg, stats, n);
    bn_apply<<<ngrid, nb, 0, stream>>>(agg, stats, g3, be3, out, n, inv_n);
}